// Round 13
// baseline (243.229 us; speedup 1.0000x reference)
//
#include <hip/hip_runtime.h>
#include <cmath>

// ---------------- problem constants ----------------
#define NLAYERS 100      // hidden layers (scan)
#define DIN     64       // input features
#define WDIM    100      // hidden width
#define NTT     4        // 4 n-tiles of 32 (128 neuron cols; bias col = 100)
#define ROWS    32       // rows per WAVE
#define WAVES   4        // waves per block
#define BROWS   (WAVES * ROWS)   // 128 rows per block
#define KS      7        // 7 k-steps of 16 -> K=112 (useful 101)
#define FRAGS   (KS * NTT)       // 28 W frags per layer
#define FPW     (FRAGS / WAVES)  // 7 frags staged per wave

typedef _Float16 half8  __attribute__((ext_vector_type(8)));
typedef _Float16 half2v __attribute__((ext_vector_type(2)));
typedef __fp16   fp16x2 __attribute__((ext_vector_type(2)));
typedef float    f32x4  __attribute__((ext_vector_type(4)));
typedef float    f32x16 __attribute__((ext_vector_type(16)));
typedef unsigned uint4v __attribute__((ext_vector_type(4)));

// ---------------- workspace layout ----------------
// wsh: [l][ks7][nt4][lane][8] — frag stride 512 halves (1024 B).
// A-frag (32x32x16, operand-swapped W^T): lane -> neuron n = nt*32+(lane&31);
// elem j -> k = ks*16 + (lane>>5)*8 + j.
//   k<100 && n<100   -> Ws[l][k][n]
//   k==100 && n<100  -> bs[l][n]      (bias row vs h col 100 == 1.0)
//   k==100 && n==100 -> 1.0           (bias col self-sustains)
// Frag layout == the global_load_lds pattern: per-lane 16B contiguous
// source, wave-uniform LDS destination base.
#define WSH_LAYER_HALVES (KS * NTT * 64 * 8)             // 14336 (28672 B)
#define WSH_HALVES       (NLAYERS * WSH_LAYER_HALVES)    // 1,433,600
#define W0_HALVES        (4 * NTT * 64 * 8)              // 8192 (input, K=64 = 4 ks)
#define BPAD_FLOATS      128                             // b_in padded; col 100 = 1.0
#define OFF_BPAD_B       ((WSH_HALVES + W0_HALVES) * 2)
#define OFF_WOUT_B       (OFF_BPAD_B + BPAD_FLOATS * 4)
#define WOUT_FLOATS      128

// ============================================================
// prep v2 (unchanged): one block per (l,ks); coalesced row reads ->
// 8KB LDS f32 tile [16k][128n] -> coalesced half8 frag stores.
// ============================================================
__global__ __launch_bounds__(256)
void actor_prep(const float* __restrict__ Win, const float* __restrict__ bin,
                const float* __restrict__ Ws,  const float* __restrict__ bs,
                const float* __restrict__ Wout,
                _Float16* __restrict__ wsh, _Float16* __restrict__ w0sh,
                float* __restrict__ bpad, float* __restrict__ woutp) {
    __shared__ float tile[16 * 128];
    const int bid = blockIdx.x, tid = threadIdx.x;
    if (bid < NLAYERS * KS) {                       // hidden-layer weights
        const int l = bid / KS, ks = bid % KS;
#pragma unroll
        for (int e = 0; e < 8; ++e) {
            int idx = tid + 256 * e;                // coalesced: tid fastest
            int kk = idx >> 7, nn = idx & 127;
            int k = ks * 16 + kk;
            float v = 0.f;
            if (k < WDIM && nn < WDIM)        v = Ws[(l * WDIM + k) * WDIM + nn];
            else if (k == WDIM && nn < WDIM)  v = bs[l * WDIM + nn];   // bias row
            else if (k == WDIM && nn == WDIM) v = 1.0f;                // bias col alive
            tile[idx] = v;
        }
        __syncthreads();
        const int lane = tid & 63, nt = tid >> 6;
        const int g = lane >> 5, n = nt * 32 + (lane & 31);
        half8 o;
#pragma unroll
        for (int j = 0; j < 8; ++j) o[j] = (_Float16)tile[(g * 8 + j) * 128 + n];
        *(half8*)(wsh + (((l * KS + ks) * NTT + nt) << 9) + lane * 8) = o;
        return;
    }
    int b2 = bid - NLAYERS * KS;
    if (b2 < 4) {                                   // input layer (K=64)
        const int ks = b2;
#pragma unroll
        for (int e = 0; e < 8; ++e) {
            int idx = tid + 256 * e;
            int kk = idx >> 7, nn = idx & 127;
            int k = ks * 16 + kk;                   // < 64
            tile[idx] = (nn < WDIM) ? Win[k * WDIM + nn] : 0.f;
        }
        __syncthreads();
        const int lane = tid & 63, nt = tid >> 6;
        const int g = lane >> 5, n = nt * 32 + (lane & 31);
        half8 o;
#pragma unroll
        for (int j = 0; j < 8; ++j) o[j] = (_Float16)tile[(g * 8 + j) * 128 + n];
        *(half8*)(w0sh + ((ks * NTT + nt) << 9) + lane * 8) = o;
        return;
    }
    // last block: padded b_in (col 100 = 1.0 seed) + padded W_out
    if (tid < BPAD_FLOATS) {
        bpad[tid] = (tid < WDIM) ? bin[tid] : (tid == WDIM ? 1.0f : 0.f);
    } else {
        int t = tid - BPAD_FLOATS;
        if (t < WOUT_FLOATS) woutp[t] = (t < WDIM) ? Wout[t] : 0.f;
    }
}

// async global->LDS, 16 B per lane, zero VGPR cost.
// g: per-lane source (base + lane*16B); l: WAVE-UNIFORM LDS frag base
// (HW adds lane*16). [m97: emits global_load_lds_dwordx4]
__device__ __forceinline__ void stage16(const _Float16* __restrict__ g,
                                        _Float16* l) {
    __builtin_amdgcn_global_load_lds(
        (const __attribute__((address_space(1))) unsigned*)g,
        (__attribute__((address_space(3))) unsigned*)l, 16, 0, 0);
}

// split fp32 -> hi/lo fp16 (layer-0 input only: keep input fidelity)
__device__ __forceinline__ void split8(const float* __restrict__ p, half8& hi, half8& lo) {
    f32x4 u0 = *(const f32x4*)p;
    f32x4 u1 = *(const f32x4*)(p + 4);
    float v[8] = {u0[0], u0[1], u0[2], u0[3], u1[0], u1[1], u1[2], u1[3]};
#pragma unroll
    for (int e = 0; e < 8; e += 2) {
        fp16x2 h = __builtin_amdgcn_cvt_pkrtz(v[e], v[e + 1]);
        float r0 = v[e]     - (float)h[0];
        float r1 = v[e + 1] - (float)h[1];
        fp16x2 l = __builtin_amdgcn_cvt_pkrtz(r0, r1);
        hi[e] = (_Float16)h[0]; hi[e + 1] = (_Float16)h[1];
        lo[e] = (_Float16)l[0]; lo[e + 1] = (_Float16)l[1];
    }
}

// RNE f16 cast pair + packed-f16 leaky -> one dword (same ops/precision
// as the original LDS epilogue: scalar RNE cast, then max(p, 0.01p) in f16)
__device__ __forceinline__ unsigned pack2(float a, float b) {
    half2v p; p[0] = (_Float16)a; p[1] = (_Float16)b;
    const half2v slope = {(_Float16)0.01f, (_Float16)0.01f};
    p = __builtin_elementwise_max(p, p * slope);
    return __builtin_bit_cast(unsigned, p);
}

// acc -> bh: leaky+f16 pack + lane-half exchange (v_permlane32_swap).
// C/D layout (m74/m101): col=b31, row=(reg&3)+8*(reg>>2)+4g. B-frag:
// lane b31 holds k=ks*16+g*8+j; j0..3 from lane b31 regs r0=8*(ks&1)+0..3,
// j4..7 from lane b31+32 same regs -> one permlane swap per dword pair.
// Bit-identical to the LDS h path (absmax constant 0.09375 since r17).
__device__ __forceinline__ void pack_bh(const f32x16 (&acc)[NTT], half8 (&bh)[KS]) {
#pragma unroll
    for (int ks = 0; ks < KS; ++ks) {
        const int r0 = 8 * (ks & 1);
        const f32x16 a = acc[ks >> 1];
        unsigned lo0 = pack2(a[r0 + 0], a[r0 + 1]);
        unsigned lo1 = pack2(a[r0 + 2], a[r0 + 3]);
        unsigned hi0 = pack2(a[r0 + 4], a[r0 + 5]);
        unsigned hi1 = pack2(a[r0 + 6], a[r0 + 7]);
        asm volatile("v_permlane32_swap_b32 %0, %1" : "+v"(lo0), "+v"(hi0));
        asm volatile("v_permlane32_swap_b32 %0, %1" : "+v"(lo1), "+v"(hi1));
        uint4v u = {lo0, lo1, hi0, hi1};
        bh[ks] = __builtin_bit_cast(half8, u);
    }
}

static __device__ const f32x16 kZero16 = {0,0,0,0, 0,0,0,0, 0,0,0,0, 0,0,0,0};

// ============================================================
// Main r30: r24 geometry (measured champion, 181us) + r23's rotating
// 3-slot W window with distance-2 ds_read prefetch.
// Post-mortem r29/r24: the cycle model does NOT close — wall 4350cy/
// CU-layer vs LDS-pipe busy ~3100cy (71%). VGPR_Count=88 (< acc64+
// bh28+addr) proves the compiler sank the 28-read wb burst to
// just-before-use: a DISTANCE-0 JIT pattern (issue 4 ds_reads, wait,
// 4 MFMAs) that exposes LDS latency (~120cy + 8-wave queue) on every
// ks group -> ~1000-1200cy/layer of unmodeled stall. r23 proved the
// explicit rotating window DOES get materialized (VGPR 164) but ran
// at 1 wave/SIMD where occupancy dominated. This combines them:
//  - wreg[3][NTT] (48 VGPR), preload ks0/ks1, prefetch ks+2 after
//    each ks's MFMAs -> every read has ~128cy (2 MFMA groups) of
//    cover + the queue amortizes across 8-12 outstanding reads.
//  - everything else bit-identical to r24: stage W(l+1) first (full
//    layer slack, drained at barrier), pack_bh in regs (permlane),
//    1 __syncthreads/layer, 2 blocks/CU (independent barrier domains
//    per SIMD -> phase diversity covers each other's stalls).
// VGPR: acc64 + bh28 + wreg48 + temps ~ 165 <= 256 (2 waves/SIMD).
// Predicted: 181 -> ~150-165us; VGPR_Count 150-175 (materialization
// signature — ~90 means the window got sunk again); absmax 0.09375.
// Pre-committed: >=178us -> distance-0 theory wrong, r24 is the
// plateau, declare ROOFLINE next round.
// ============================================================
__global__ __launch_bounds__(256, 2)
void actor_main(const float* __restrict__ x,
                const _Float16* __restrict__ wsh,
                const _Float16* __restrict__ w0sh,
                const float* __restrict__ bpad,
                const float* __restrict__ woutp,
                const float* __restrict__ bout,
                float* __restrict__ out) {
    __shared__ __align__(16) _Float16 wlds[2 * WSH_LAYER_HALVES];  // 57344 B
    const int tid  = threadIdx.x;
    const int lane = tid & 63;
    const int wid  = tid >> 6;                   // 0..3
    const int g = lane >> 5, b31 = lane & 31;
    const int rowbase = blockIdx.x * BROWS + wid * ROWS;   // my wave's 32 rows

    f32x16 acc[NTT];                 //  64 VGPR: 4 independent MFMA chains
    half8 bh[KS];                    //  28 VGPR: B-frags (next-layer input)
    half8 wreg[3][NTT];              //  48 VGPR: rotating W window (dist-2)

    // ---- stage W(0) -> buf0 (async; overlaps entire input layer) ----
#pragma unroll
    for (int f = 0; f < FPW; ++f) {
        const int fr = wid * FPW + f;
        stage16(wsh + fr * 512 + lane * 8, wlds + fr * 512);
    }

    // ---- input layer (K=64 = 4 k-steps of 16), x hi/lo f16 split ----
    {
        half8 w0[4][NTT];
#pragma unroll
        for (int ks = 0; ks < 4; ++ks)
#pragma unroll
            for (int nt = 0; nt < NTT; ++nt)
                w0[ks][nt] = *(const half8*)(w0sh + (ks * NTT + nt) * 512 + lane * 8);
#pragma unroll
        for (int nt = 0; nt < NTT; ++nt)
#pragma unroll
            for (int qd = 0; qd < 4; ++qd) {
                f32x4 tq = *(const f32x4*)(bpad + nt * 32 + 8 * qd + 4 * g);
#pragma unroll
                for (int r = 0; r < 4; ++r) acc[nt][4 * qd + r] = tq[r];
            }
        const float* xr = x + (rowbase + b31) * DIN;
#pragma unroll
        for (int ks = 0; ks < 4; ++ks) {
            half8 xhi, xlo;
            split8(xr + ks * 16 + g * 8, xhi, xlo);
#pragma unroll
            for (int nt = 0; nt < NTT; ++nt) {
                acc[nt] = __builtin_amdgcn_mfma_f32_32x32x16_f16(w0[ks][nt], xhi, acc[nt], 0, 0, 0);
                acc[nt] = __builtin_amdgcn_mfma_f32_32x32x16_f16(w0[ks][nt], xlo, acc[nt], 0, 0, 0);
            }
        }
    }
    pack_bh(acc, bh);                // h0 in regs
    __syncthreads();                 // drains W(0) staging (vmcnt(0) + barrier)

    // -------- 100 hidden layers: 1 barrier/layer, windowed W pipeline ------
#pragma unroll 1
    for (int l = 0; l < NLAYERS; ++l) {
        const _Float16* rb = wlds + (l & 1) * WSH_LAYER_HALVES;        // W(l)
        _Float16* sb = wlds + ((l + 1) & 1) * WSH_LAYER_HALVES;        // W(l+1) dest
        const int ln = (l + 1 < NLAYERS) ? l + 1 : NLAYERS - 1;
        const _Float16* wn = wsh + ln * WSH_LAYER_HALVES;

        // issue next-layer staging FIRST (max slack before the barrier drain)
#pragma unroll
        for (int f = 0; f < FPW; ++f) {
            const int fr = wid * FPW + f;
            stage16(wn + fr * 512 + lane * 8, sb + fr * 512);
        }
        // W window preload: ks0, ks1 (8 ds_read_b128 in flight)
#pragma unroll
        for (int kp = 0; kp < 2; ++kp)
#pragma unroll
            for (int nt = 0; nt < NTT; ++nt)
                wreg[kp][nt] = *(const half8*)(rb + (kp * NTT + nt) * 512 + lane * 8);
        // 28 MFMAs (4 indep chains) with distance-2 ds_read prefetch:
        // each ks's frags were requested 2 groups (~128cy MFMA) earlier
#pragma unroll
        for (int ks = 0; ks < KS; ++ks) {
            const int s = ks % 3;
#pragma unroll
            for (int nt = 0; nt < NTT; ++nt)
                acc[nt] = __builtin_amdgcn_mfma_f32_32x32x16_f16(
                    wreg[s][nt], bh[ks], (ks == 0 ? kZero16 : acc[nt]), 0, 0, 0);
            if (ks + 2 < KS) {
                const int s2 = (ks + 2) % 3;
#pragma unroll
                for (int nt = 0; nt < NTT; ++nt)
                    wreg[s2][nt] = *(const half8*)(rb + ((ks + 2) * NTT + nt) * 512 + lane * 8);
            }
        }
        if (l < NLAYERS - 1)
            pack_bh(acc, bh);        // next layer's input (regs only)
        __syncthreads();             // staging drained + buffers flip
    }
    // acc[nt] = pre-activation of layer 99 (f32) for all 128 neurons

    // ---------------- head: leaky + dot(W_out), wave-local ----------------
    float s = 0.f;
#pragma unroll
    for (int nt = 0; nt < NTT; ++nt)
#pragma unroll
        for (int qd = 0; qd < 4; ++qd) {
            f32x4 w4 = *(const f32x4*)(woutp + nt * 32 + 8 * qd + 4 * g);
#pragma unroll
            for (int r = 0; r < 4; ++r) {
                float a = acc[nt][4 * qd + r];
                float v = fmaxf(a, 0.01f * a);
                s += v * w4[r];
            }
        }
    s += __shfl_xor(s, 32);          // combine the two k-groups (same batch row)
    if (lane < 32) {
        float tot = s + bout[0];
        out[rowbase + b31] = tanhf(tot) * 4.5f + 5.5f;   // (tanh+1)/2*9 + 1
    }
}

extern "C" void kernel_launch(void* const* d_in, const int* in_sizes, int n_in,
                              void* d_out, int out_size, void* d_ws, size_t ws_size,
                              hipStream_t stream) {
    const float* x    = (const float*)d_in[0];
    const float* Win  = (const float*)d_in[1];
    const float* bin  = (const float*)d_in[2];
    const float* Ws   = (const float*)d_in[3];
    const float* bs   = (const float*)d_in[4];
    const float* Wout = (const float*)d_in[5];
    const float* bout = (const float*)d_in[6];
    float* out = (float*)d_out;

    char* ws = (char*)d_ws;
    _Float16* wsh  = (_Float16*)ws;
    _Float16* w0sh = wsh + WSH_HALVES;
    float* bpad  = (float*)(ws + OFF_BPAD_B);
    float* woutp = (float*)(ws + OFF_WOUT_B);

    hipLaunchKernelGGL(actor_prep, dim3(NLAYERS * KS + 4 + 1), dim3(256), 0, stream,
                       Win, bin, Ws, bs, Wout, wsh, w0sh, bpad, woutp);

    const int nrows = in_sizes[0] / DIN;   // 65536
    hipLaunchKernelGGL(actor_main, dim3(nrows / BROWS), dim3(WAVES * 64), 0, stream,
                       x, wsh, w0sh, bpad, woutp, bout, out);
}